// Round 1
// baseline (101.460 us; speedup 1.0000x reference)
//
#include <hip/hip_runtime.h>

// Closed-form constant-curvature rollout.
// State y = [r(3), R(9 row-major), ux, uy].
// Per segment: ux,uy const => R(s) = R0 * exp(s*uhat), uhat = skew((ux,uy,0)).
// exp(s*uhat) = I + A*uhat + B*uhat^2, A = sin(s*th)/th, B = (1-cos(s*th))/th^2.
// r(s) = r0 + R0 * (B*uy, -B*ux, A).
// Reference clamps at kmax = (int)(l/DS): s = min(t, kmax)*DS; next segment
// starts from state at s_end = kmax*DS.

namespace {

constexpr float kL0 = 0.1f;
constexpr float kD  = 0.0075f;
constexpr float kDS = 0.005f;
constexpr int   kT    = 29;   // round((0.1+0.04)/0.005)+1
constexpr int   kNSeg = 3;

__device__ __forceinline__ void exp_and_p(float ux, float uy, float s,
                                          float E[9], float p[3]) {
    float th2   = ux * ux + uy * uy;
    float theta = sqrtf(th2);
    float A, Bv, c;
    if (theta < 1e-5f) {
        // series: A = s(1 - phi^2/6..), B = s^2/2 (1 - ..); phi <= 1.4e-6 here
        A  = s;
        Bv = 0.5f * s * s;
        c  = 1.0f;
    } else {
        float phi = s * theta;
        float sh, ch;
        sincosf(0.5f * phi, &sh, &ch);
        float si  = 2.0f * sh * ch;   // sin(phi)
        float sh2 = 2.0f * sh * sh;   // 1 - cos(phi), no cancellation
        A  = si / theta;
        Bv = sh2 / th2;
        c  = 1.0f - sh2;
    }
    float Aux = A * ux, Auy = A * uy;
    E[0] = 1.0f - Bv * uy * uy;
    E[1] = Bv * ux * uy;
    E[2] = Auy;
    E[3] = E[1];
    E[4] = 1.0f - Bv * ux * ux;
    E[5] = -Aux;
    E[6] = -Auy;
    E[7] = Aux;
    E[8] = c;
    p[0] = Bv * uy;
    p[1] = -Bv * ux;
    p[2] = A;
}

// Advance frame (r,R) through segment m evaluated at step index t (t>=kT
// means "to segment end"). Leaves ux,uy of this segment in out params.
__device__ __forceinline__ void seg_state(const float* __restrict__ actions,
                                          int b, int m, int t,
                                          float r[3], float R[9],
                                          float& ux, float& uy) {
    const float a0 = actions[(size_t)b * 9 + 3 * m + 0];
    const float a1 = actions[(size_t)b * 9 + 3 * m + 1];
    const float a2 = actions[(size_t)b * 9 + 3 * m + 2];
    float l  = kL0 + a0;          // float32 add, matches jnp
    float md = l * kD;
    ux = a2 / (-md);              // IEEE f32 div, matches jnp
    uy = a1 / md;
    int kmax = (int)(l / kDS);    // trunc toward zero == astype(int32)
    int tc = t < kmax ? t : kmax;
    float s = (float)tc * kDS;

    float E[9], p[3];
    exp_and_p(ux, uy, s, E, p);

    float nr[3], NR[9];
#pragma unroll
    for (int i = 0; i < 3; ++i) {
        nr[i] = r[i] + R[3 * i + 0] * p[0] + R[3 * i + 1] * p[1] + R[3 * i + 2] * p[2];
#pragma unroll
        for (int j = 0; j < 3; ++j) {
            NR[3 * i + j] = R[3 * i + 0] * E[j]
                          + R[3 * i + 1] * E[3 + j]
                          + R[3 * i + 2] * E[6 + j];
        }
    }
#pragma unroll
    for (int i = 0; i < 3; ++i) r[i] = nr[i];
#pragma unroll
    for (int i = 0; i < 9; ++i) R[i] = NR[i];
}

__global__ __launch_bounds__(256) void rollout(const float* __restrict__ actions,
                                               float* __restrict__ out, int B) {
    int b = blockIdx.x * blockDim.x + threadIdx.x;
    if (b >= B) return;
    int row = blockIdx.y;         // 0..3*kT-1, uniform per block
    int n = row / kT;             // segment (uniform)
    int t = row - n * kT;         // step within segment (uniform)

    float r[3] = {0.f, 0.f, 0.f};
    float R[9] = {1.f, 0.f, 0.f, 0.f, 1.f, 0.f, 0.f, 0.f, 1.f};
    float ux, uy;

    // chain through completed segments (uniform branches; kmax <= 28 < kT)
    if (n >= 1) seg_state(actions, b, 0, kT, r, R, ux, uy);
    if (n >= 2) seg_state(actions, b, 1, kT, r, R, ux, uy);
    // current segment at (clamped) step t
    seg_state(actions, b, n, t, r, R, ux, uy);

    float o[14];
#pragma unroll
    for (int i = 0; i < 3; ++i) {
        o[i] = r[i];
#pragma unroll
        for (int j = 0; j < 3; ++j) o[3 + 3 * i + j] = R[3 * i + j];
    }
    o[12] = ux;
    o[13] = uy;

    size_t base = ((size_t)row * (size_t)B + (size_t)b) * 14;
    float2* o2 = reinterpret_cast<float2*>(out + base);  // 8B-aligned (56B stride)
#pragma unroll
    for (int i = 0; i < 7; ++i) o2[i] = make_float2(o[2 * i], o[2 * i + 1]);
}

} // namespace

extern "C" void kernel_launch(void* const* d_in, const int* in_sizes, int n_in,
                              void* d_out, int out_size, void* d_ws, size_t ws_size,
                              hipStream_t stream) {
    const float* actions = (const float*)d_in[0];
    float* out = (float*)d_out;
    int B = in_sizes[0] / 9;                 // 16384
    dim3 block(256);
    dim3 grid((B + 255) / 256, kNSeg * kT);  // (64, 87)
    rollout<<<grid, block, 0, stream>>>(actions, out, B);
}

// Round 3
// 89.043 us; speedup vs baseline: 1.1394x; 1.1394x over previous
//
#include <hip/hip_runtime.h>

// Closed-form constant-curvature rollout.
// State y = [r(3), R(9 row-major), ux, uy].
// Per segment: ux,uy const => R(s) = R0 * exp(s*uhat), uhat = skew((ux,uy,0)).
// exp(s*uhat) = I + A*uhat + B*uhat^2, A = sin(phi)/theta, B = (1-cos(phi))/theta^2,
// phi = s*theta. r(s) = r0 + R0 * (B*uy, -B*ux, A).
// Reference clamps at kmax = (int)(l/DS): s = min(t, kmax)*DS; next segment
// starts from the state at s_end = kmax*DS.
//
// Perf structure: thread <-> batch element for compute; block output
// (256 batches x 14 floats = 14336 B contiguous) staged through LDS and
// written as coalesced float4s.

namespace {

constexpr float kL0 = 0.1f;
constexpr float kD  = 0.0075f;
constexpr float kDS = 0.005f;
constexpr int   kT    = 29;   // round((0.1+0.04)/0.005)+1
constexpr int   kNSeg = 3;

__device__ __forceinline__ float fast_rcp(float x) {
    return __builtin_amdgcn_rcpf(x);   // v_rcp_f32, ~1 ulp
}

__device__ __forceinline__ void exp_and_p(float ux, float uy, float s,
                                          float E[9], float p[3]) {
    float th2   = ux * ux + uy * uy;
    float theta = sqrtf(th2);
    float A, Bv, c;
    if (theta < 1e-5f) {
        A  = s;
        Bv = 0.5f * s * s;
        c  = 1.0f;
    } else {
        float phi = s * theta;
        float sh, ch;
        __sincosf(0.5f * phi, &sh, &ch);   // native v_sin/v_cos, phi/2 <= ~1 rad
        float si  = 2.0f * sh * ch;        // sin(phi)
        float sh2 = 2.0f * sh * sh;        // 1 - cos(phi), no cancellation
        float rth = fast_rcp(theta);
        A  = si * rth;
        Bv = sh2 * rth * rth;
        c  = 1.0f - sh2;
    }
    float Aux = A * ux, Auy = A * uy;
    E[0] = 1.0f - Bv * uy * uy;
    E[1] = Bv * ux * uy;
    E[2] = Auy;
    E[3] = E[1];
    E[4] = 1.0f - Bv * ux * ux;
    E[5] = -Aux;
    E[6] = -Auy;
    E[7] = Aux;
    E[8] = c;
    p[0] = Bv * uy;
    p[1] = -Bv * ux;
    p[2] = A;
}

// Advance frame (r,R) through segment m evaluated at step index t (t>=kT
// means "to segment end"). Leaves ux,uy of this segment in out params.
__device__ __forceinline__ void seg_state(const float* __restrict__ actions,
                                          int b, int m, int t,
                                          float r[3], float R[9],
                                          float& ux, float& uy) {
    const float a0 = actions[(size_t)b * 9 + 3 * m + 0];
    const float a1 = actions[(size_t)b * 9 + 3 * m + 1];
    const float a2 = actions[(size_t)b * 9 + 3 * m + 2];
    float l  = kL0 + a0;          // f32 add, matches jnp
    float md = l * kD;
    ux = a2 / (-md);              // exact IEEE div: ux,uy are outputs
    uy = a1 / md;
    int kmax = (int)(l / kDS);    // exact IEEE div + trunc == astype(int32)
    int tc = t < kmax ? t : kmax;
    float s = (float)tc * kDS;

    float E[9], p[3];
    exp_and_p(ux, uy, s, E, p);

    float nr[3], NR[9];
#pragma unroll
    for (int i = 0; i < 3; ++i) {
        nr[i] = r[i] + R[3 * i + 0] * p[0] + R[3 * i + 1] * p[1] + R[3 * i + 2] * p[2];
#pragma unroll
        for (int j = 0; j < 3; ++j) {
            NR[3 * i + j] = R[3 * i + 0] * E[j]
                          + R[3 * i + 1] * E[3 + j]
                          + R[3 * i + 2] * E[6 + j];
        }
    }
#pragma unroll
    for (int i = 0; i < 3; ++i) r[i] = nr[i];
#pragma unroll
    for (int i = 0; i < 9; ++i) R[i] = NR[i];
}

__global__ __launch_bounds__(256) void rollout(const float* __restrict__ actions,
                                               float* __restrict__ out, int B) {
    __shared__ float smem[256 * 14];

    int b = blockIdx.x * blockDim.x + threadIdx.x;
    int row = blockIdx.y;         // 0..3*kT-1, uniform per block
    int n = row / kT;             // segment (uniform)
    int t = row - n * kT;         // step within segment (uniform)

    float r[3] = {0.f, 0.f, 0.f};
    float R[9] = {1.f, 0.f, 0.f, 0.f, 1.f, 0.f, 0.f, 0.f, 1.f};
    float ux, uy;

    // chain through completed segments (uniform branches; kmax <= 28 < kT)
    if (n >= 1) seg_state(actions, b, 0, kT, r, R, ux, uy);
    if (n >= 2) seg_state(actions, b, 1, kT, r, R, ux, uy);
    // current segment at (clamped) step t
    seg_state(actions, b, n, t, r, R, ux, uy);

    // stage this thread's 14 outputs in LDS (stride 14: 4-way conflicts, cheap)
    float* my = &smem[threadIdx.x * 14];
    my[0] = r[0];  my[1] = r[1];  my[2] = r[2];
#pragma unroll
    for (int i = 0; i < 9; ++i) my[3 + i] = R[i];
    my[12] = ux;
    my[13] = uy;
    __syncthreads();

    // coalesced block store: 256*14 floats = 896 float4 (16B-aligned base)
    size_t blockbase = ((size_t)row * (size_t)B + (size_t)blockIdx.x * 256) * 14;
    float4* o4 = reinterpret_cast<float4*>(out + blockbase);
    const float4* s4 = reinterpret_cast<const float4*>(smem);
#pragma unroll
    for (int k = 0; k < 3; ++k) {
        int q = k * 256 + threadIdx.x;
        o4[q] = s4[q];
    }
    if (threadIdx.x < 128) {
        int q = 768 + threadIdx.x;
        o4[q] = s4[q];
    }
}

} // namespace

extern "C" void kernel_launch(void* const* d_in, const int* in_sizes, int n_in,
                              void* d_out, int out_size, void* d_ws, size_t ws_size,
                              hipStream_t stream) {
    const float* actions = (const float*)d_in[0];
    float* out = (float*)d_out;
    int B = in_sizes[0] / 9;                 // 16384
    dim3 block(256);
    dim3 grid((B + 255) / 256, kNSeg * kT);  // (64, 87)
    rollout<<<grid, block, 0, stream>>>(actions, out, B);
}